// Round 10
// baseline (518.786 us; speedup 1.0000x reference)
//
#include <hip/hip_runtime.h>
#include <cstdint>

#define TT 300   // timesteps
#define TC 75    // TT/4
#define NBATCH 4

typedef float pf2 __attribute__((ext_vector_type(2)));   // packs to v_pk_fma_f32
typedef _Float16 h8t __attribute__((ext_vector_type(8)));  // 4 VGPRs = MFMA f16 A/B frag
typedef float f32x4 __attribute__((ext_vector_type(4)));   // MFMA C/D frag

// PSP + refractory IIR step, exact op order of the reference scan.
__device__ __forceinline__ void psp_step(float z, float& gp, float& hp, float& gr, float& hr, float& s_out) {
    hp = 0.90483741803595957f * (hp + gp);      // a_sr = exp(-1/10)
    gp = 0.90483741803595957f * gp + z;
    hr = 0.36787944117144233f * (hr + gr);      // a_rf = exp(-1)
    gr = 0.36787944117144233f * gr;
    float u = 0.27182818284590452f * hp + (-54.365636569180904f) * hr; // c_sr*hp + c_rf*hr
    float s = (u >= 10.0f) ? 1.0f : 0.0f;
    gr += s;
    s_out = s;
}

// Per-neuron scan over T, 12-step chunks, [p][300] layout (used for L0 and L6).
template <int R>
__global__ void k_scan_redp(const float* __restrict__ z, float* __restrict__ s,
                            int n_neur, int pstride) {
    int i = blockIdx.x * 64 + threadIdx.x;
    if (i >= n_neur) return;
    const float* zp = z + (size_t)i * TT;
    float* sp = s + (size_t)i * TT;
    float gp = 0.f, hp = 0.f, gr = 0.f, hr = 0.f;
#pragma unroll 1
    for (int c = 0; c < 25; ++c) {
        const float* p = zp + c * 12;
        float4 a0 = *(const float4*)(p);
        float4 a1 = *(const float4*)(p + 4);
        float4 a2 = *(const float4*)(p + 8);
#pragma unroll
        for (int r = 1; r < R; ++r) {
            const float* pr = p + (size_t)r * pstride;
            float4 b0 = *(const float4*)(pr);
            float4 b1 = *(const float4*)(pr + 4);
            float4 b2 = *(const float4*)(pr + 8);
            a0.x += b0.x; a0.y += b0.y; a0.z += b0.z; a0.w += b0.w;
            a1.x += b1.x; a1.y += b1.y; a1.z += b1.z; a1.w += b1.w;
            a2.x += b2.x; a2.y += b2.y; a2.z += b2.z; a2.w += b2.w;
        }
        float4 o0, o1, o2;
        psp_step(a0.x, gp, hp, gr, hr, o0.x);
        psp_step(a0.y, gp, hp, gr, hr, o0.y);
        psp_step(a0.z, gp, hp, gr, hr, o0.z);
        psp_step(a0.w, gp, hp, gr, hr, o0.w);
        psp_step(a1.x, gp, hp, gr, hr, o1.x);
        psp_step(a1.y, gp, hp, gr, hr, o1.y);
        psp_step(a1.z, gp, hp, gr, hr, o1.z);
        psp_step(a1.w, gp, hp, gr, hr, o1.w);
        psp_step(a2.x, gp, hp, gr, hr, o2.x);
        psp_step(a2.y, gp, hp, gr, hr, o2.y);
        psp_step(a2.z, gp, hp, gr, hr, o2.z);
        psp_step(a2.w, gp, hp, gr, hr, o2.w);
        float* q = sp + c * 12;
        *(float4*)(q) = o0;
        *(float4*)(q + 4) = o1;
        *(float4*)(q + 8) = o2;
    }
}

// Scan for L5 output: reads z5 in [tc][p][16] layout (p = n*4096 + f), writes f16
// spikes S16 [n][t][4096]. Wave reads are 64 lanes x 64B contiguous = 4KB segments.
__global__ void k_scan16_f16(const float* __restrict__ z, _Float16* __restrict__ s16) {
    int i = blockIdx.x * 64 + threadIdx.x;     // 16384 neurons, grid 256 x 64
    int n = i >> 12, f = i & 4095;
    const float* zp = z + (size_t)i * 16;
    _Float16* sp = s16 + ((size_t)n * TT) * 4096 + f;
    float gp = 0.f, hp = 0.f, gr = 0.f, hr = 0.f;
#define SC16_CHUNK(TCI, NTT) do {                                              \
    const float* pp = zp + (size_t)(TCI) * (16384 * 16);                       \
    float4 a0 = *(const float4*)(pp);                                          \
    float4 a1 = *(const float4*)(pp + 4);                                      \
    float4 a2 = *(const float4*)(pp + 8);                                      \
    float4 a3 = *(const float4*)(pp + 12);                                     \
    float zv[16] = {a0.x,a0.y,a0.z,a0.w,a1.x,a1.y,a1.z,a1.w,                   \
                    a2.x,a2.y,a2.z,a2.w,a3.x,a3.y,a3.z,a3.w};                  \
    _Pragma("unroll")                                                          \
    for (int tt = 0; tt < (NTT); ++tt) {                                       \
        float o;                                                               \
        psp_step(zv[tt], gp, hp, gr, hr, o);                                   \
        sp[(size_t)((TCI) * 16 + tt) * 4096] = (_Float16)o;                    \
    }                                                                          \
} while (0)
#pragma unroll 1
    for (int tcc = 0; tcc < 18; ++tcc) SC16_CHUNK(tcc, 16);
    SC16_CHUNK(18, 12);
#undef SC16_CHUNK
}

// Fused scan-pool-scan for L3 output: reads z3 [tc][p][16] (p = ((n*C+c)*H+y)*W+x),
// emits f16 spikes conv-native [n][c/8][y2][x2][t][8].
template <int C, int H2, int W2>
__global__ void __launch_bounds__(256) k_spsq16(const float* __restrict__ z,
                                                _Float16* __restrict__ s16) {
    constexpr int H = 2 * H2, W = 2 * W2;
    constexpr int NP = NBATCH * C * H * W;
    constexpr int C8 = C / 8;
    __shared__ _Float16 tile[16 * C];

    int i = blockIdx.x * 256 + threadIdx.x;    // grid exact: N*C*H2*W2*4 threads
    int q = i & 3;
    int p = i >> 2;
    int c  = p % C;
    int x2 = (p / C) % W2;
    int y2 = (p / (C * W2)) % H2;
    int n  = p / (C * W2 * H2);
    int dy = q >> 1, dx = q & 1;
    int pz = ((n * C + c) * H + 2 * y2 + dy) * W + 2 * x2 + dx;
    const float* zp = z + (size_t)pz * 16;

    int tid = threadIdx.x;
    int wt  = tid & 15;
    int wc8 = tid >> 4;
    int p0 = blockIdx.x * 64;                  // block's site (C-aligned p)
    int wx2 = (p0 / C) % W2;
    int wy2 = (p0 / (C * W2)) % H2;
    int wn  = p0 / (C * W2 * H2);
    _Float16* wbase = s16 + ((((size_t)(wn * C8 + wc8) * H2 + wy2) * W2 + wx2) * TT) * 8;

    float gp = 0.f, hp = 0.f, gr = 0.f, hr = 0.f;   // conv neuron IIR
    float Gp = 0.f, Hp = 0.f, Gr = 0.f, Hr = 0.f;   // pooled neuron IIR
#define SPSQ_CHUNK(TCI, NTT) do {                                              \
    const float* pp = zp + (size_t)(TCI) * (NP * 16);                          \
    float4 a0 = *(const float4*)(pp);                                          \
    float4 a1 = *(const float4*)(pp + 4);                                      \
    float4 a2 = *(const float4*)(pp + 8);                                      \
    float4 a3 = *(const float4*)(pp + 12);                                     \
    float zv[16] = {a0.x,a0.y,a0.z,a0.w,a1.x,a1.y,a1.z,a1.w,                   \
                    a2.x,a2.y,a2.z,a2.w,a3.x,a3.y,a3.z,a3.w};                  \
    float ov[16];                                                              \
    _Pragma("unroll")                                                          \
    for (int tt = 0; tt < (NTT); ++tt) {                                       \
        float sq;                                                              \
        psp_step(zv[tt], gp, hp, gr, hr, sq);                                  \
        float t1 = sq + __shfl_xor(sq, 1, 64);                                 \
        float pool = t1 + __shfl_xor(t1, 2, 64);                               \
        psp_step(11.0f * pool, Gp, Hp, Gr, Hr, ov[tt]);                        \
    }                                                                          \
    __syncthreads();                                                           \
    if (q == 0) {                                                              \
        _Pragma("unroll")                                                      \
        for (int tt = 0; tt < (NTT); ++tt)                                     \
            tile[tt * C + c] = (_Float16)ov[tt];                               \
    }                                                                          \
    __syncthreads();                                                           \
    if (tid < 16 * C8 && wt < (NTT)) {                                         \
        h8t v = *(const h8t*)(tile + wt * C + wc8 * 8);                        \
        *(h8t*)(wbase + (size_t)((TCI) * 16 + wt) * 8) = v;                    \
    }                                                                          \
} while (0)
#pragma unroll 1
    for (int tcc = 0; tcc < 18; ++tcc) SPSQ_CHUNK(tcc, 16);
    SPSQ_CHUNK(18, 12);
#undef SPSQ_CHUNK
}

// --- weight-pack device helpers (f16 hi/lo split: w == hi + lo * 2^-12) ---
__device__ __forceinline__ void pack_wmfma_item(int i, const float* __restrict__ w,
                                                _Float16* __restrict__ wm, int CIN, int COUT) {
    int lane = i & 63;
    int r = i >> 6;
    int ver = r & 1; r >>= 1;
    int KC = CIN >> 5, CT = COUT >> 4;
    int ct = r % CT; r /= CT;
    int kc = r % KC;
    int tap = r / KC;
    int ky = tap / 3, kx = tap % 3;
    int co  = ct * 16 + (lane & 15);
    int ci0 = kc * 32 + (lane >> 4) * 8;
    _Float16 out[8];
#pragma unroll
    for (int j = 0; j < 8; ++j) {
        float wf = w[((co * CIN + ci0 + j) * 3 + ky) * 3 + kx];
        _Float16 hi = (_Float16)wf;
        out[j] = ver ? (_Float16)((wf - (float)hi) * 4096.0f) : hi;
    }
    *(h8t*)(wm + (size_t)i * 8) = *(h8t*)out;
}

__device__ __forceinline__ void pack_wfc_item(int i, const float* __restrict__ w,
                                              _Float16* __restrict__ wm, int FIN, int COUT) {
    int lane = i & 63;
    int r = i >> 6;
    int ver = r & 1; r >>= 1;
    int CT = COUT >> 4;
    int ct = r % CT;
    int kg = r / CT;
    int co = ct * 16 + (lane & 15);
    int f0 = kg * 32 + (lane >> 4) * 8;
    _Float16 out[8];
#pragma unroll
    for (int j = 0; j < 8; ++j) {
        float wf = w[(size_t)co * FIN + f0 + j];
        _Float16 hi = (_Float16)wf;
        out[j] = ver ? (_Float16)((wf - (float)hi) * 4096.0f) : hi;
    }
    *(h8t*)(wm + (size_t)i * 8) = *(h8t*)out;
}

__device__ __forceinline__ void pack_wl1_item(int i, const float* __restrict__ w,
                                              _Float16* __restrict__ wm) {
    int lane = i & 63;
    int r = i >> 6;
    int ver = r & 1;
    int ch = (r >> 1) & 1;
    int kc = r >> 2;
    int co = ch * 16 + (lane & 15);
    int k0 = kc * 32 + (lane >> 4) * 8;
    _Float16 out[8];
#pragma unroll
    for (int j = 0; j < 8; ++j) {
        int k = k0 + j;
        int ky = k >> 4, slot = k & 15, kx = slot >> 1, ci = slot & 1;
        float wf = (ky < 5 && kx < 5) ? w[((co * 2 + ci) * 5 + ky) * 5 + kx] : 0.f;
        _Float16 hif = (_Float16)wf;
        out[j] = ver ? (_Float16)((wf - (float)hif) * 4096.0f) : hif;
    }
    *(h8t*)(wm + (size_t)i * 8) = *(h8t*)out;
}

// Front kernel: blocks [0,2400) = 4x4 sum-pool * 11.0 (N,2,128,128,T)->(N,2,32,32,T);
// blocks [2400,3481) = all 4 weight packs (276,736 items). One launch, fewer gaps.
__global__ void k_front(const float* __restrict__ x, float* __restrict__ z,
                        const float* __restrict__ w1, const float* __restrict__ w2,
                        const float* __restrict__ w3, const float* __restrict__ w4a,
                        _Float16* __restrict__ wl1m, _Float16* __restrict__ wm2,
                        _Float16* __restrict__ wm3, _Float16* __restrict__ wm4) {
    if (blockIdx.x < 2400) {
        int idx = blockIdx.x * 256 + threadIdx.x;   // = NBATCH*2*32*32*TC exactly
        int tc = idx % TC;
        int p  = idx / TC;
        int w  = p % 32;
        int h  = (p / 32) % 32;
        int nc = p / (32 * 32);
        const float* base = x + (((size_t)nc * 128 + h * 4) * 128 + w * 4) * TT + tc * 4;
        float ax = 0.f, ay = 0.f, az = 0.f, aw = 0.f;
#pragma unroll
        for (int i = 0; i < 4; ++i)
#pragma unroll
            for (int j = 0; j < 4; ++j) {
                float4 v = *(const float4*)(base + ((size_t)i * 128 + j) * TT);
                ax += v.x; ay += v.y; az += v.z; aw += v.w;
            }
        float4 o; o.x = 11.0f * ax; o.y = 11.0f * ay; o.z = 11.0f * az; o.w = 11.0f * aw;
        *(float4*)(z + (size_t)p * TT + tc * 4) = o;
    } else {
        int i = (blockIdx.x - 2400) * 256 + threadIdx.x;
        if (i < 768)          pack_wl1_item(i, w1, wl1m);
        else if (i < 5376)    pack_wmfma_item(i - 768, w2, wm2, 32, 64);
        else if (i < 14592)   pack_wmfma_item(i - 5376, w3, wm3, 64, 64);
        else if (i < 276736)  pack_wfc_item(i - 14592, w4a, wm4, 4096, 256);
    }
}

// Fused L1 (v4): 5x5 conv (2->32) MFMA + psp + 2x2 pool + psp -> s2h f16 conv-native.
// Block = (n, ch co-half, xh x-octet, y2 pool-row) owns ALL 300 t (IIR in VGPRs).
// v4 vs v3: stage stride 34 halves (17 words, odd -> 17*tl mod 32 all-distinct for
// tl in [0,16): conflict-free b128 reads) shrinks LDS 56.7 -> 53.1 KB -> 3 blocks/CU
// (VGPR must stay <= 170). Same 32-t tiles, T14 async staging, 3 barriers/tile.
// Numerics: identical values and op order -> absmax unchanged (0.0).
__global__ void __launch_bounds__(256, 2) k_l1_fused(const float* __restrict__ s0,
                                                     const _Float16* __restrict__ wl1,
                                                     _Float16* __restrict__ s2h) {
    constexpr int NT = 10;                    // ceil(300/32); tile 9 has 12 valid t
    constexpr int SS = 34;                    // stage stride in halves (17 words, odd)
    __shared__ _Float16 stage[7 * 32 * SS];   // 15232 B
    __shared__ float    trans[256 * 33];      // 33792 B
    __shared__ _Float16 tile[4 * 32 * 16];    //  4096 B   -> total 53120 B

    int bid = blockIdx.x;                     // grid 512 = n4 * ch2 * xh4 * y2_16
    int y2 = bid & 15;
    int xh = (bid >> 4) & 3;
    int ch = (bid >> 6) & 1;
    int n  = bid >> 7;
    int tid = threadIdx.x;
    int lane = tid & 63;
    int wv = tid >> 6;          // 4 waves: (yy, xq)
    int tl = lane & 15;
    int hi = lane >> 4;
    int yy = wv >> 1;
    int xq = wv & 1;

    int q     = tid & 3;        // scan role: dy=q>>1, dx=q&1 (lane bits 0-1 -> shfl pool)
    int co_s  = (tid >> 2) & 15;
    int x2l_s = tid >> 6;
    int wt  = tid & 31;         // writer role: all 256 threads (4wx x 2wc8 x 32t)
    int wc8 = (tid >> 5) & 1;
    int wx  = tid >> 6;

    // stage geometry: thread handles (tq = tid&7, lx, ci) for ALL 7 rows (r = ii).
    int tq = tid & 7;
    int lx = (tid >> 3) & 15;
    int ci = tid >> 7;
    int gx = xh * 8 + lx - 2;
    bool gxok = (gx >= 0 && gx < 32);
    size_t boff = (((size_t)(n * 2 + ci) * 32) * 32 + (gxok ? gx : 0)) * TT + tq * 4;  // gy=0
    int adr0 = (tq * 4) * SS + lx * 2 + ci;

    const h8t* wv4 = (const h8t*)wl1;
    h8t wfr[3][2];
#pragma unroll
    for (int kc = 0; kc < 3; ++kc) {
        wfr[kc][0] = wv4[((kc * 2 + ch) * 2 + 0) * 64 + lane];
        wfr[kc][1] = wv4[((kc * 2 + ch) * 2 + 1) * 64 + lane];
    }

    float gp = 0.f, hp = 0.f, gr = 0.f, hr = 0.f;
    float Gp = 0.f, Hp = 0.f, Gr = 0.f, Hr = 0.f;

    // prologue prefetch: tile 0 (t 0..31, all < 300)
    float4 pf[7];
#pragma unroll
    for (int ii = 0; ii < 7; ++ii) {
        int gy = y2 * 2 + ii - 2;
        pf[ii] = make_float4(0.f, 0.f, 0.f, 0.f);
        if (gxok && gy >= 0 && gy < 32)
            pf[ii] = *(const float4*)(s0 + boff + (size_t)gy * (32 * TT));
    }

#pragma unroll 1
    for (int tc = 0; tc < NT; ++tc) {
        // stage write from prefetched regs (f32 -> f16)
#pragma unroll
        for (int ii = 0; ii < 7; ++ii) {
            int a = adr0 + ii * (32 * SS);
            stage[a + 0 * SS] = (_Float16)pf[ii].x;
            stage[a + 1 * SS] = (_Float16)pf[ii].y;
            stage[a + 2 * SS] = (_Float16)pf[ii].z;
            stage[a + 3 * SS] = (_Float16)pf[ii].w;
        }
        // issue next tile's loads now — in flight across MFMA + scan phases
        if (tc + 1 < NT) {
#pragma unroll
            for (int ii = 0; ii < 7; ++ii) {
                int gy = y2 * 2 + ii - 2;
                float4 v = make_float4(0.f, 0.f, 0.f, 0.f);
                if (gxok && gy >= 0 && gy < 32 && (tc + 1) * 32 + tq * 4 + 3 < TT)
                    v = *(const float4*)(s0 + boff + (size_t)gy * (32 * TT) + (tc + 1) * 32);
                pf[ii] = v;
            }
        }
        __syncthreads();   // [B] stage ready
        // MFMA: wave (yy,xq) -> 16 co x 8 xo-halves x 32 t (two 16-t groups).
        f32x4 ah4[2][4], al4[2][4];
#pragma unroll
        for (int tg = 0; tg < 2; ++tg)
#pragma unroll
            for (int xi = 0; xi < 4; ++xi) {
                ah4[tg][xi] = (f32x4){0.f, 0.f, 0.f, 0.f};
                al4[tg][xi] = (f32x4){0.f, 0.f, 0.f, 0.f};
            }
#pragma unroll
        for (int kc = 0; kc < 3; ++kc) {
            int rowb = yy + 2 * kc + (hi >> 1);
#pragma unroll
            for (int tg = 0; tg < 2; ++tg) {
#pragma unroll
                for (int xi = 0; xi < 4; ++xi) {
                    int xo = xq * 4 + xi;
                    const uint32_t* lp = (const uint32_t*)(stage + (rowb * 32 + tg * 16 + tl) * SS + xo * 2 + (hi & 1) * 8);
                    union { uint32_t u[4]; h8t h; } bu;
                    bu.u[0] = lp[0]; bu.u[1] = lp[1]; bu.u[2] = lp[2]; bu.u[3] = lp[3];
                    ah4[tg][xi] = __builtin_amdgcn_mfma_f32_16x16x32_f16(wfr[kc][0], bu.h, ah4[tg][xi], 0, 0, 0);
                    al4[tg][xi] = __builtin_amdgcn_mfma_f32_16x16x32_f16(wfr[kc][1], bu.h, al4[tg][xi], 0, 0, 0);
                }
            }
        }
        // transpose -> trans[neuron][t]; neuron = (x2l*16+co)*4 + dy*2 + dx.
#pragma unroll
        for (int tg = 0; tg < 2; ++tg)
#pragma unroll
            for (int xi = 0; xi < 4; ++xi) {
                int xo = xq * 4 + xi;
#pragma unroll
                for (int r = 0; r < 4; ++r) {
                    float u = ah4[tg][xi][r] + al4[tg][xi][r] * 2.44140625e-4f;
                    int rowt = ((xo >> 1) * 16 + hi * 4 + r) * 4 + yy * 2 + (xo & 1);
                    trans[rowt * 33 + tg * 16 + tl] = u;
                }
            }
        __syncthreads();   // [C] trans ready
        // scan: each thread = 1 conv neuron; quad (lane bits 0-1) pools via shfl.
#pragma unroll
        for (int t = 0; t < 32; ++t) {
            float u = trans[tid * 33 + t];
            float sq;
            psp_step(u, gp, hp, gr, hr, sq);
            float t1 = sq + __shfl_xor(sq, 1, 64);
            float pool = t1 + __shfl_xor(t1, 2, 64);
            float ov;
            psp_step(11.0f * pool, Gp, Hp, Gr, Hr, ov);
            if (q == 0) tile[(x2l_s * 32 + t) * 16 + co_s] = (_Float16)ov;
        }
        __syncthreads();   // [D] tile ready
        // write pooled spikes: [n][cg8 4][y2 16][x2 16][t 300][8]
        {
            int tg = tc * 32 + wt;
            if (tg < TT) {
                h8t v = *(const h8t*)(tile + (wx * 32 + wt) * 16 + wc8 * 8);
                int cg8 = ch * 2 + wc8;
                int x2g = xh * 4 + wx;
                *(h8t*)(s2h + ((((size_t)(n * 4 + cg8) * 16 + y2) * 16 + x2g) * (size_t)TT + tg) * 8) = v;
            }
        }
    }
}

// MFMA 3x3 conv (pad 1). Input: f16 spikes [n][ci/8][y][x][t][8]. Output z in
// [tc][p][16] layout (full-line block ownership, XW even). launch_bounds (256,2):
// round-4's (256,4) forced acc spill; HW reaches 4-6 blocks/CU via LDS/VGPR naturally.
template <int CIN, int COUT, int H, int W, int YPB, int XSPL>
__global__ void __launch_bounds__(256, 2) k_conv_mfma(const _Float16* __restrict__ s16,
                                                      const _Float16* __restrict__ wm,
                                                      float* __restrict__ z) {
    constexpr int NT = 19;          // ceil(300/16)
    constexpr int KC = CIN / 32;
    constexpr int CH = CIN / 8;
    constexpr int XW = W / XSPL;    // output x per block
    constexpr int XL = XW + 2;
    constexpr int CT = COUT / 16;
    constexpr int XPW = XW / 4;
    constexpr int ROWS = YPB + 2;
    constexpr int NP = NBATCH * COUT * H * W;
    __shared__ _Float16 lds[ROWS * XL * 16 * CIN];

    int bid = blockIdx.x;
    int tc = bid % NT;
    int r0 = bid / NT;
    int yb = (r0 % (H / YPB)) * YPB;
    r0 /= (H / YPB);
    int xh = r0 % XSPL;
    int n  = r0 / XSPL;
    int xb = xh * XW;
    int tid = threadIdx.x;

    constexpr int TOT = ROWS * XL * CH * 16;
    for (int i = tid; i < TOT; i += 256) {
        int t   = i & 15;
        int c   = (i >> 4) % CH;
        int xc  = ((i >> 4) / CH) % XL;
        int row = ((i >> 4) / CH) / XL;
        int tg = tc * 16 + t;
        int xi = xb + xc - 1;
        int yi = yb + row - 1;
        h8t v;
#pragma unroll
        for (int e = 0; e < 8; ++e) v[e] = (_Float16)0.0f;
        if (xi >= 0 && xi < W && yi >= 0 && yi < H && tg < TT)
            v = *(const h8t*)(s16 + ((((size_t)(n * CH + c) * H + yi) * W + xi) * TT + tg) * 8);
        int swz = (CIN == 32) ? ((t >> 1) & 3) : (t & 7);
        int off = ((row * XL + xc) * 16 + t) * CIN + ((c ^ swz) << 3);
        *(h8t*)(lds + off) = v;
    }
    __syncthreads();

    int lane = tid & 63;
    int wv   = tid >> 6;
    int tl   = lane & 15;
    int hi   = lane >> 4;
    const h8t* wmv = (const h8t*)wm;
    int swz = (CIN == 32) ? ((tl >> 1) & 3) : (tl & 7);

#pragma unroll
    for (int yy = 0; yy < YPB; ++yy) {
        f32x4 acc_h[XPW][CT], acc_l[XPW][CT];
#pragma unroll
        for (int a = 0; a < XPW; ++a)
#pragma unroll
            for (int b = 0; b < CT; ++b) {
                acc_h[a][b] = (f32x4){0.f, 0.f, 0.f, 0.f};
                acc_l[a][b] = (f32x4){0.f, 0.f, 0.f, 0.f};
            }
#pragma unroll
        for (int ky = 0; ky < 3; ++ky) {
#pragma unroll
            for (int kx = 0; kx < 3; ++kx) {
                int tap = ky * 3 + kx;
#pragma unroll
                for (int kc = 0; kc < KC; ++kc) {
                    h8t bf[XPW];
#pragma unroll
                    for (int xi = 0; xi < XPW; ++xi) {
                        int x = wv * XPW + xi;
                        int c = kc * 4 + hi;
                        int off = (((yy + ky) * XL + (x + kx)) * 16 + tl) * CIN + ((c ^ swz) << 3);
                        bf[xi] = *(const h8t*)(lds + off);
                    }
#pragma unroll
                    for (int ct = 0; ct < CT; ++ct) {
                        size_t wbase = ((size_t)(tap * KC + kc) * CT + ct) * 2;
                        h8t ah = wmv[(wbase + 0) * 64 + lane];
                        h8t al = wmv[(wbase + 1) * 64 + lane];
#pragma unroll
                        for (int xi = 0; xi < XPW; ++xi) {
                            acc_h[xi][ct] = __builtin_amdgcn_mfma_f32_16x16x32_f16(ah, bf[xi], acc_h[xi][ct], 0, 0, 0);
                            acc_l[xi][ct] = __builtin_amdgcn_mfma_f32_16x16x32_f16(al, bf[xi], acc_l[xi][ct], 0, 0, 0);
                        }
                    }
                }
            }
        }
        // C/D layout: col = lane&15 (= t), row = (lane>>4)*4 + r (= cout)
#pragma unroll
        for (int xi = 0; xi < XPW; ++xi) {
            int x = xb + wv * XPW + xi;
#pragma unroll
            for (int ct = 0; ct < CT; ++ct) {
#pragma unroll
                for (int r = 0; r < 4; ++r) {
                    int co = ct * 16 + hi * 4 + r;
                    int pz = ((n * COUT + co) * H + (yb + yy)) * W + x;
                    z[((size_t)tc * NP + pz) * 16 + tl]
                        = acc_h[xi][ct][r] + acc_l[xi][ct][r] * 2.44140625e-4f;
                }
            }
        }
    }
}

// MFMA FC: out[n][co][t] = sum_f w[co][f] * s16[n][t][f]. Output z6 [n][co][300] f32.
template <int FIN, int OUT>
__global__ void __launch_bounds__(256) k_fc_mfma(const _Float16* __restrict__ s16,
                                                 const _Float16* __restrict__ wm,
                                                 float* __restrict__ z) {
    constexpr int NT = 19;
    constexpr int CT = OUT / 16;
    constexpr int KCH = 512;
    constexpr int NK = FIN / KCH;
    __shared__ _Float16 lds[KCH * 16];   // 16 KB

    int bid = blockIdx.x;           // grid = (CT/4) * NBATCH * NT
    int tc = bid % NT;
    int n  = (bid / NT) % NBATCH;
    int cg = bid / (NT * NBATCH);
    int tid = threadIdx.x;
    int lane = tid & 63, wv = tid >> 6;
    int tl = lane & 15, hi = lane >> 4;
    int ct = cg * 4 + wv;

    f32x4 acc_h = (f32x4){0.f, 0.f, 0.f, 0.f};
    f32x4 acc_l = (f32x4){0.f, 0.f, 0.f, 0.f};
    const h8t* wmv = (const h8t*)wm;

    for (int kb = 0; kb < NK; ++kb) {
        __syncthreads();
#pragma unroll
        for (int j = 0; j < 4; ++j) {
            int chunk = tid + j * 256;
            int c = chunk & 63;
            int t = chunk >> 6;
            int tg = tc * 16 + t;
            h8t v;
#pragma unroll
            for (int e = 0; e < 8; ++e) v[e] = (_Float16)0.0f;
            if (tg < TT) v = *(const h8t*)(s16 + ((size_t)(n * TT + tg) * FIN + kb * KCH + c * 8));
            *(h8t*)(lds + ((t * 64 + (c ^ (t & 7))) << 3)) = v;
        }
        __syncthreads();
#pragma unroll
        for (int kc = 0; kc < KCH / 32; ++kc) {
            int c = kc * 4 + hi;
            h8t bf = *(const h8t*)(lds + ((tl * 64 + (c ^ (tl & 7))) << 3));
            size_t wbase = ((size_t)((kb * (KCH / 32) + kc) * CT + ct)) * 2;
            h8t ah = wmv[(wbase + 0) * 64 + lane];
            h8t al = wmv[(wbase + 1) * 64 + lane];
            acc_h = __builtin_amdgcn_mfma_f32_16x16x32_f16(ah, bf, acc_h, 0, 0, 0);
            acc_l = __builtin_amdgcn_mfma_f32_16x16x32_f16(al, bf, acc_l, 0, 0, 0);
        }
    }
    int tg = tc * 16 + tl;
    if (tg < TT) {
#pragma unroll
        for (int r = 0; r < 4; ++r) {
            int co = ct * 16 + hi * 4 + r;
            z[(size_t)(n * OUT + co) * TT + tg] = acc_h[r] + acc_l[r] * 2.44140625e-4f;
        }
    }
}

// FC with packed fp32 FMA over the t dimension (tiny L7 11x256).
template <int OUT, int FIN, int OPER, int FSPLIT>
__global__ void k_fc_a(const float* __restrict__ s, const float* __restrict__ wgt,
                       float* __restrict__ z) {
    constexpr int OG = OUT / OPER, FCH = FIN / FSPLIT;
    int idx = blockIdx.x * 256 + threadIdx.x;
    if (idx >= NBATCH * OG * TC * FSPLIT) return;
    int tc = idx % TC;
    int og = (idx / TC) % OG;
    int n  = (idx / (TC * OG)) % NBATCH;
    int sp = idx / (TC * OG * NBATCH);
    const float* sb = s + (size_t)n * FIN * TT + (size_t)sp * FCH * TT + tc * 4;
    const float* wb = wgt + (size_t)sp * FCH;
    pf2 acc[OPER][2];
#pragma unroll
    for (int k = 0; k < OPER; ++k) { acc[k][0] = (pf2){0.f, 0.f}; acc[k][1] = (pf2){0.f, 0.f}; }
#pragma unroll 2
    for (int f = 0; f < FCH; f += 4) {
        float4 s0 = *(const float4*)(sb + (size_t)(f + 0) * TT);
        float4 s1 = *(const float4*)(sb + (size_t)(f + 1) * TT);
        float4 s2 = *(const float4*)(sb + (size_t)(f + 2) * TT);
        float4 s3 = *(const float4*)(sb + (size_t)(f + 3) * TT);
        pf2 s0a = {s0.x, s0.y}, s0b = {s0.z, s0.w};
        pf2 s1a = {s1.x, s1.y}, s1b = {s1.z, s1.w};
        pf2 s2a = {s2.x, s2.y}, s2b = {s2.z, s2.w};
        pf2 s3a = {s3.x, s3.y}, s3b = {s3.z, s3.w};
#pragma unroll
        for (int k = 0; k < OPER; ++k) {
            float4 wv = *(const float4*)(wb + (size_t)(og * OPER + k) * FIN + f);
            pf2 wx = {wv.x, wv.x}, wy = {wv.y, wv.y}, wz = {wv.z, wv.z}, ww = {wv.w, wv.w};
            pf2 a0 = acc[k][0], a1 = acc[k][1];
            a0 = __builtin_elementwise_fma(wx, s0a, a0);
            a0 = __builtin_elementwise_fma(wy, s1a, a0);
            a0 = __builtin_elementwise_fma(wz, s2a, a0);
            a0 = __builtin_elementwise_fma(ww, s3a, a0);
            a1 = __builtin_elementwise_fma(wx, s0b, a1);
            a1 = __builtin_elementwise_fma(wy, s1b, a1);
            a1 = __builtin_elementwise_fma(wz, s2b, a1);
            a1 = __builtin_elementwise_fma(ww, s3b, a1);
            acc[k][0] = a0; acc[k][1] = a1;
        }
    }
#pragma unroll
    for (int k = 0; k < OPER; ++k) {
        float4 o;
        o.x = acc[k][0].x; o.y = acc[k][0].y; o.z = acc[k][1].x; o.w = acc[k][1].y;
        *(float4*)(z + ((size_t)sp * NBATCH * OUT + (size_t)n * OUT + og * OPER + k) * TT + tc * 4) = o;
    }
}

extern "C" void kernel_launch(void* const* d_in, const int* in_sizes, int n_in,
                              void* d_out, int out_size, void* d_ws, size_t ws_size,
                              hipStream_t stream) {
    const float* s_in = (const float*)d_in[0]; // (4,2,128,128,300)
    const float* w1   = (const float*)d_in[1]; // (32,2,5,5)
    const float* w2   = (const float*)d_in[2]; // (64,32,3,3)
    const float* w3   = (const float*)d_in[3]; // (64,64,3,3)
    const float* w4a  = (const float*)d_in[4]; // (256,4096)
    const float* w4b  = (const float*)d_in[5]; // (11,256)
    float* out = (float*)d_out;                // (4,11,300)

    // Workspace map (floats): Z 39,321,600 | Sb 9,830,400 | WP 56,896.
    // Z: z3 [tc][65536][16] = 19.92M floats at [0..); z5 [tc][16384][16] = 4.98M;
    //    S16 @ Z+25M (2.46M f); wm4 @ Z+28M (1.05M f); wl1m @ Z+30M.
    // Sb: s0 f32 [0..2.46M); s2h f16 @ Sb+2.5M; s4h f16 @ Sb+5M (sequential liveness);
    //     s6 f32 reuses Sb[0..).
    float* Z  = (float*)d_ws;
    float* Sb = Z + 39321600;
    float* WP = Sb + 9830400;
    _Float16* wm2 = (_Float16*)(WP + 1600);
    _Float16* wm3 = (_Float16*)(WP + 1600 + 18432);
    _Float16* S16 = (_Float16*)(Z + 25000000);
    _Float16* wm4 = (_Float16*)(Z + 28000000);
    _Float16* wl1m = (_Float16*)(Z + 30000000);          // 6144 halves
    float* s0 = Sb;                                      // f32 (4,2,32,32,300)
    _Float16* s2h = (_Float16*)(Sb + 2500000);           // f16 [n][4][16][16][300][8]
    _Float16* s4h = (_Float16*)(Sb + 5000000);           // f16 [n][8][8][8][300][8]

    auto g64 = [](int n) { return (n + 63) / 64; };

    // front: 4x4 pool (blocks 0..2399) + all weight packs (blocks 2400..3480)
    k_front<<<3481, 256, 0, stream>>>(s_in, Z, w1, w2, w3, w4a, wl1m, wm2, wm3, wm4);
    k_scan_redp<1><<<g64(8192), 64, 0, stream>>>(Z, s0, 8192, 0);

    // L1 fused v4 (32-t tiles, 53.1KB LDS -> 3 blocks/CU): grid 512.
    k_l1_fused<<<512, 256, 0, stream>>>(s0, wl1m, s2h);

    // L3 conv 3x3 (32->64, 16x16) MFMA, YPB=2 XSPL=4: z3 [tc][p][16] @ Z.
    // grid 19*8*4*4 = 2432; LDS 24.6KB -> ~5-6 blocks/CU.
    k_conv_mfma<32, 64, 16, 16, 2, 4><<<2432, 256, 0, stream>>>(s2h, wm2, Z);
    // L3 psp + 2x2 pool + L4 psp -> s4h f16 conv-native. 256 blocks.
    k_spsq16<64, 8, 8><<<256, 256, 0, stream>>>(Z, s4h);

    // L5 conv 3x3 (64->64, 8x8) MFMA, YPB=1 XSPL=2: z5 [tc][p][16] @ Z. grid 1216.
    k_conv_mfma<64, 64, 8, 8, 1, 2><<<1216, 256, 0, stream>>>(s4h, wm3, Z);
    // psp scan -> f16 spikes [n][t][f] @ S16 (16384 neurons).
    k_scan16_f16<<<256, 64, 0, stream>>>(Z, S16);

    // L6: fc 4096->256 MFMA: z6 (4,256,300) @ Z. grid = 4 cog * 4 n * 19 tc = 304.
    k_fc_mfma<4096, 256><<<304, 256, 0, stream>>>(S16, wm4, Z);
    k_scan_redp<1><<<g64(1024), 64, 0, stream>>>(Z, Sb, 1024, 0);

    // L7: fc 256->11 + psp -> out
    k_fc_a<11, 256, 1, 1><<<(3300 + 255) / 256, 256, 0, stream>>>(Sb, w4b, Z);
    k_scan_redp<1><<<1, 64, 0, stream>>>(Z, out, 44, 0);
}